// Round 13
// baseline (538.105 us; speedup 1.0000x reference)
//
#include <hip/hip_runtime.h>
#include <hip/hip_bf16.h>

#define N_NODES 50000
#define N_EDGES 800000
#define N_GRAPHS 128
#define HID 128
#define NK 3
#define NL 4
#define NC 10
#define BN_EPS 1e-5f
#define SCAN_G ((N_NODES + 255) / 256)
#define NSLICE 32

// fill_src bucketed scatter
#define BKT_SZ 8192
#define NBKT 7                    // ceil(50000/8192)
#define FP_CHK 256
#define FP_E (N_EDGES / FP_CHK)   // 3125

// full-range packed-LDS histogram
#define H_CHK 64
#define H_E (N_EDGES / H_CHK)     // 12500 edges/chunk  (<= 65535 -> fits u16)
#define PKW (N_NODES / 2)         // 25000 packed words = 100 KB LDS

// fused aggregate+GEMM tile
#define AG_BM 32
#define UA_STRIDE 392             // 384 + 8 pad halfs (2-way bank alias = free)

typedef __attribute__((ext_vector_type(8))) _Float16 half8;
typedef __attribute__((ext_vector_type(4))) float floatx4;
typedef __attribute__((ext_vector_type(2))) float float2v;
typedef __attribute__((ext_vector_type(2))) _Float16 half2v;
typedef __attribute__((ext_vector_type(4))) _Float16 half4v;

__device__ __forceinline__ float tanh_fast(float x) {
    float ax = fabsf(x);
    float t = __expf(-2.0f * ax);
    float r = (1.0f - t) / (1.0f + t);
    return copysignf(r, x);
}

// ------- degree histogram: full node range in 100 KB LDS, u16-packed counts.
__global__ __launch_bounds__(256) void hist_lds_kernel(const int* __restrict__ row,
                                                       const int* __restrict__ col,
                                                       unsigned* __restrict__ pr,
                                                       unsigned* __restrict__ pc) {
    __shared__ unsigned hh[PKW];
    int tid = threadIdx.x;
    const int4* arr = (const int4*)(blockIdx.y ? col : row);
    unsigned* out = (blockIdx.y ? pc : pr) + (size_t)blockIdx.x * PKW;
    uint4* hh4 = (uint4*)hh;
    const uint4 z4 = {0u, 0u, 0u, 0u};
    for (int i = tid; i < PKW / 4; i += 256) hh4[i] = z4;
    __syncthreads();
    int base4 = blockIdx.x * (H_E / 4);
    for (int i = tid; i < H_E / 4; i += 256) {
        int4 v = arr[base4 + i];
        atomicAdd(&hh[v.x >> 1], 1u << ((v.x & 1) << 4));
        atomicAdd(&hh[v.y >> 1], 1u << ((v.y & 1) << 4));
        atomicAdd(&hh[v.z >> 1], 1u << ((v.z & 1) << 4));
        atomicAdd(&hh[v.w >> 1], 1u << ((v.w & 1) << 4));
    }
    __syncthreads();
    uint4* out4 = (uint4*)out;
    for (int i = tid; i < PKW / 4; i += 256) out4[i] = hh4[i];
}

// reduce packed partials -> degr/degc (unpack BEFORE summing)
__global__ __launch_bounds__(256) void hist_reduce_kernel(const unsigned* __restrict__ pr,
                                                          const unsigned* __restrict__ pc,
                                                          int* __restrict__ degr,
                                                          int* __restrict__ degc) {
    int w = blockIdx.x * 256 + threadIdx.x;
    if (w >= PKW) return;
    unsigned rlo = 0, rhi = 0, clo = 0, chi = 0;
    for (int ch = 0; ch < H_CHK; ++ch) {
        unsigned a = pr[(size_t)ch * PKW + w];
        unsigned b = pc[(size_t)ch * PKW + w];
        rlo += a & 0xFFFFu; rhi += a >> 16;
        clo += b & 0xFFFFu; chi += b >> 16;
    }
    ((int2*)degr)[w] = make_int2((int)rlo, (int)rhi);
    ((int2*)degc)[w] = make_int2((int)clo, (int)chi);
}

// ------------------------------------------------ hierarchical scan (3 kernels)
__global__ __launch_bounds__(256) void scan1_kernel(const int* __restrict__ degc,
                                                    int* __restrict__ csr_off,
                                                    int* __restrict__ blocksum) {
    __shared__ int buf[256];
    int tid = threadIdx.x;
    int i = blockIdx.x * 256 + tid;
    int v = (i < N_NODES) ? degc[i] : 0;
    buf[tid] = v;
    __syncthreads();
    for (int d = 1; d < 256; d <<= 1) {
        int t = (tid >= d) ? buf[tid - d] : 0;
        __syncthreads();
        buf[tid] += t;
        __syncthreads();
    }
    if (i < N_NODES) csr_off[i] = buf[tid] - v;
    if (tid == 255) blocksum[blockIdx.x] = buf[255];
}

__global__ __launch_bounds__(256) void scan2_kernel(int* __restrict__ blocksum) {
    __shared__ int buf[256];
    int tid = threadIdx.x;
    int v = (tid < SCAN_G) ? blocksum[tid] : 0;
    buf[tid] = v;
    __syncthreads();
    for (int d = 1; d < 256; d <<= 1) {
        int t = (tid >= d) ? buf[tid - d] : 0;
        __syncthreads();
        buf[tid] += t;
        __syncthreads();
    }
    if (tid < SCAN_G) blocksum[tid] = buf[tid] - v;   // exclusive, in place
}

__global__ __launch_bounds__(256) void scan3_kernel(const int* __restrict__ blocksum,
                                                    int* __restrict__ csr_off,
                                                    int* __restrict__ cursor) {
    int i = blockIdx.x * 256 + threadIdx.x;
    if (i < N_NODES) {
        int v = csr_off[i] + blocksum[blockIdx.x];
        csr_off[i] = v;
        cursor[i] = v;
    }
    if (i == 0) csr_off[N_NODES] = N_EDGES;
}

// ---------- counting-sort scatter: 4-B records (src node id only).
__global__ __launch_bounds__(256) void fill_src_kernel(const int* __restrict__ col,
                                                       const int* __restrict__ row,
                                                       int* __restrict__ cursor,
                                                       int* __restrict__ esrc) {
    int bkt = blockIdx.x & 7;
    if (bkt >= NBKT) return;          // bucket 7 is empty padding
    int chunk = blockIdx.x >> 3;
    int base = bkt * BKT_SZ;
    int e0 = chunk * FP_E;
    for (int e = e0 + threadIdx.x; e < e0 + FP_E; e += 256) {
        unsigned c = (unsigned)(col[e] - base);
        if (c < BKT_SZ) {
            int pos = atomicAdd(&cursor[base + (int)c], 1);
            esrc[pos] = row[e];
        }
    }
}

// --------------------- fp32->fp16 converts + fc_w transpose, one dispatch.
__global__ void prep16_kernel(const float4* __restrict__ a, int n4a,
                              const float4* __restrict__ b, int n4b,
                              half4v* __restrict__ da, half4v* __restrict__ db,
                              const float* __restrict__ fc_w,
                              _Float16* __restrict__ w2t) {
    int i = blockIdx.x * blockDim.x + threadIdx.x;
    if (i < n4a + n4b) {
        const float4* src; half4v* dst; int idx;
        if (i < n4a) { src = a; dst = da; idx = i; }
        else { src = b; dst = db; idx = i - n4a; }
        float4 f = src[idx];
        half4v o;
        o.x = (_Float16)f.x; o.y = (_Float16)f.y; o.z = (_Float16)f.z; o.w = (_Float16)f.w;
        dst[idx] = o;
        return;
    }
    int idx = i - (n4a + n4b);
    if (idx >= NL * NK * HID * HID) return;
    int ii = idx & (HID - 1);
    int j = (idx >> 7) & (HID - 1);
    int kl = idx >> 14;          // l*3 + k
    int k = kl % 3;
    int l = kl / 3;
    w2t[((size_t)(l * HID + j)) * (NK * HID) + k * HID + ii] = (_Float16)fc_w[idx];
}

// -------------------------------------------------- fp16 MFMA GEMM, BM=64
// (round-11 winner; now used only for the embedding GEMM, Kd=128, no BN)
__global__ __launch_bounds__(256) void gemm_f16_kernel(
        const _Float16* __restrict__ A, const _Float16* __restrict__ W,
        const float* __restrict__ bias, _Float16* __restrict__ C16,
        int M, int Kd) {
    __shared__ _Float16 sA[64 * 40], sB[128 * 40];    // stride 40 halfs
    int tid = threadIdx.x;
    int bm = blockIdx.x * 64;
    int wave = tid >> 6, lane = tid & 63;
    int ln = lane & 15, quad = lane >> 4;
    int wy = wave >> 1, wx = wave & 1;
    int srow = tid >> 2, scol = (tid & 3) << 3;
    floatx4 acc[2][4] = {};
    const half8 zv = {0, 0, 0, 0, 0, 0, 0, 0};

    half8 pA, pB[2];
    bool av0 = (bm + srow) < M;
    const size_t aoff0 = (size_t)(bm + srow) * Kd + scol;
    const size_t woff0 = (size_t)srow * Kd + scol;
    const size_t woff1 = (size_t)(srow + 64) * Kd + scol;

#define LOAD_TILE(K0)                                                          \
    do {                                                                       \
        pB[0] = *(const half8*)(W + woff0 + (K0));                             \
        pB[1] = *(const half8*)(W + woff1 + (K0));                             \
        pA = av0 ? *(const half8*)(A + aoff0 + (K0)) : zv;                     \
    } while (0)

    LOAD_TILE(0);
    for (int k0 = 0; k0 < Kd; k0 += 32) {
        __syncthreads();
        *(half8*)&sA[srow * 40 + scol] = pA;
        *(half8*)&sB[srow * 40 + scol] = pB[0];
        *(half8*)&sB[(srow + 64) * 40 + scol] = pB[1];
        __syncthreads();
        if (k0 + 32 < Kd) LOAD_TILE(k0 + 32);   // overlaps with MFMA below
        half8 a[2], b[4];
        int kq = quad * 8;
#pragma unroll
        for (int i = 0; i < 2; ++i)
            a[i] = *(const half8*)&sA[(wy * 32 + i * 16 + ln) * 40 + kq];
#pragma unroll
        for (int j = 0; j < 4; ++j)
            b[j] = *(const half8*)&sB[(wx * 64 + j * 16 + ln) * 40 + kq];
#pragma unroll
        for (int i = 0; i < 2; ++i)
#pragma unroll
            for (int j = 0; j < 4; ++j)
                acc[i][j] = __builtin_amdgcn_mfma_f32_16x16x32_f16(a[i], b[j], acc[i][j], 0, 0, 0);
    }
#undef LOAD_TILE

    // epilogue: C/D layout col = lane&15, row = quad*4 + reg
#pragma unroll
    for (int j = 0; j < 4; ++j) {
        int gc = wx * 64 + j * 16 + ln;
        float bv = bias ? bias[gc] : 0.f;
#pragma unroll
        for (int i = 0; i < 2; ++i) {
#pragma unroll
            for (int r = 0; r < 4; ++r) {
                int gr = bm + wy * 32 + i * 16 + quad * 4 + r;
                if (gr < M) C16[(size_t)gr * HID + gc] = (_Float16)(acc[i][j][r] + bv);
            }
        }
    }
}

// ---- reduce BN slices -> fused scale/shift (one tiny block per layer)
__global__ __launch_bounds__(128) void bn_finalize_kernel(const float* __restrict__ slices,
                                                          const float* __restrict__ gamma,
                                                          const float* __restrict__ beta,
                                                          float* __restrict__ sc_sh) {
    int t = threadIdx.x;   // channel
    float s = 0.f, q = 0.f;
    for (int sl = 0; sl < NSLICE; ++sl) {
        s += slices[sl * (2 * HID) + t];
        q += slices[sl * (2 * HID) + HID + t];
    }
    const float invN = 1.0f / (float)N_NODES;
    float mean = s * invN;
    float var = q * invN - mean * mean;
    float scale = gamma[t] * rsqrtf(var + BN_EPS);
    sc_sh[t] = scale;
    sc_sh[HID + t] = beta[t] - mean * scale;
}

// ===== FUSED aggregate + GEMM: one block = 32-node tile.
// Phase 1: round-8 gather loop (32-lane sub-groups, 2 nodes/wave/pass,
// 4 passes) writes u-rows into LDS uA[32][392] instead of global u —
// kills the 77 MB/layer u round trip. Rows for n>=N_NODES stay zero
// (matches old zero-row convention; BN stats identical).
// Phase 2: MFMA K-loop, A-fragments from uA, B staged from w2t (L2-res).
// LDS 36.4 KB -> 4 blocks/CU = 16 waves/CU: gather occupancy preserved.
__global__ __launch_bounds__(256) void agg_gemm_kernel(
        const int* __restrict__ csr_off, const int* __restrict__ esrc,
        const int* __restrict__ degr, const int* __restrict__ degc,
        const char* __restrict__ h16, const _Float16* __restrict__ W,
        _Float16* __restrict__ C16, float* __restrict__ bnsum,
        const float* __restrict__ pw, const float* __restrict__ pb,
        const float* __restrict__ mu, const float* __restrict__ isg) {
    __shared__ _Float16 uA[AG_BM * UA_STRIDE];   // 25.1 KB
    __shared__ _Float16 sB[128 * 40];            // 10.2 KB
    __shared__ float bsum[HID], bsq[HID];
    int tid = threadIdx.x;
    if (tid < HID) { bsum[tid] = 0.f; bsq[tid] = 0.f; }
    int wave = tid >> 6, lane = tid & 63;
    int sub = lane >> 5;          // which node in the wave
    int sl = lane & 31;           // lane within 32-group
    int base = sub << 5;          // shfl source base
    int bm = blockIdx.x * AG_BM;

    float pw0 = pw[0], pw1 = pw[1], pw2 = pw[2], pw3 = pw[3];
    float pb0 = pb[0], pb1 = pb[1];
    float m00 = mu[0], m01 = mu[1], m10 = mu[2], m11 = mu[3], m20 = mu[4], m21 = mu[5];
    float s00 = isg[0], s01 = isg[1], s10 = isg[2], s11 = isg[3], s20 = isg[4], s21 = isg[5];
    const char* hb = h16 + sl * 8;

    // ---------- phase 1: aggregate 32 nodes into uA
#pragma unroll 1
    for (int pass = 0; pass < 4; ++pass) {
        int lnode = pass * 8 + wave * 2 + sub;   // 0..31
        int n = bm + lnode;
        floatx4 a0 = {0.f, 0.f, 0.f, 0.f}, a1 = a0, a2 = a0;
        if (n < N_NODES) {
            int beg = csr_off[n], end = csr_off[n + 1];
            float py = rsqrtf((float)degc[n] + 1.0f);
            for (int chunk = beg; chunk < end; chunk += 32) {
                int ce = chunk + sl;
                int rsrc = (ce < end) ? esrc[ce] : 0;
                float px = rsqrtf((float)degr[rsrc] + 1.0f);
                int roff = rsrc << 8;     // byte offset into fp16 h row
                float ps0 = tanh_fast(px * pw0 + py * pw1 + pb0);
                float ps1 = tanh_fast(px * pw2 + py * pw3 + pb1);
                float d0 = ps0 - m00, d1 = ps1 - m01;
                float w0 = __expf(-0.5f * (d0 * d0 * s00 * s00 + d1 * d1 * s01 * s01));
                d0 = ps0 - m10; d1 = ps1 - m11;
                float w1 = __expf(-0.5f * (d0 * d0 * s10 * s10 + d1 * d1 * s11 * s11));
                d0 = ps0 - m20; d1 = ps1 - m21;
                float w2 = __expf(-0.5f * (d0 * d0 * s20 * s20 + d1 * d1 * s21 * s21));
                int m = end - chunk; if (m > 32) m = 32;
                int t = 0;
                for (; t + 8 <= m; t += 8) {
                    int ro[8];
#pragma unroll
                    for (int s = 0; s < 8; ++s) ro[s] = __shfl(roff, base + t + s);
                    half4v hv[8];
#pragma unroll
                    for (int s = 0; s < 8; ++s) hv[s] = *(const half4v*)(hb + (unsigned)ro[s]);
#pragma unroll
                    for (int s = 0; s < 8; ++s) {
                        float wx = __shfl(w0, base + t + s);
                        float wy = __shfl(w1, base + t + s);
                        float wz = __shfl(w2, base + t + s);
                        floatx4 hf = {(float)hv[s].x, (float)hv[s].y, (float)hv[s].z, (float)hv[s].w};
                        a0 += wx * hf;
                        a1 += wy * hf;
                        a2 += wz * hf;
                    }
                }
                for (; t < m; ++t) {
                    int ro = __shfl(roff, base + t);
                    float wx = __shfl(w0, base + t);
                    float wy = __shfl(w1, base + t);
                    float wz = __shfl(w2, base + t);
                    half4v hv = *(const half4v*)(hb + (unsigned)ro);
                    floatx4 hf = {(float)hv.x, (float)hv.y, (float)hv.z, (float)hv.w};
                    a0 += wx * hf;
                    a1 += wy * hf;
                    a2 += wz * hf;
                }
            }
        }
        _Float16* urow = &uA[lnode * UA_STRIDE + sl * 4];
        half4v o0, o1, o2;
        o0.x = (_Float16)a0.x; o0.y = (_Float16)a0.y; o0.z = (_Float16)a0.z; o0.w = (_Float16)a0.w;
        o1.x = (_Float16)a1.x; o1.y = (_Float16)a1.y; o1.z = (_Float16)a1.z; o1.w = (_Float16)a1.w;
        o2.x = (_Float16)a2.x; o2.y = (_Float16)a2.y; o2.z = (_Float16)a2.z; o2.w = (_Float16)a2.w;
        *(half4v*)(urow)       = o0;
        *(half4v*)(urow + 128) = o1;
        *(half4v*)(urow + 256) = o2;
    }

    // ---------- phase 2: C(32x128) = uA(32x384) @ W(128x384)^T
    int ln = lane & 15, quad = lane >> 4;
    int wy = wave >> 1, wx = wave & 1;       // wy: 16-row half, wx: 64-col half
    int srow = tid >> 2, scol = (tid & 3) << 3;
    floatx4 acc[4] = {};
    const size_t woff0 = (size_t)srow * (NK * HID) + scol;
    const size_t woff1 = (size_t)(srow + 64) * (NK * HID) + scol;
    half8 pB0 = *(const half8*)(W + woff0);
    half8 pB1 = *(const half8*)(W + woff1);
    for (int k0 = 0; k0 < NK * HID; k0 += 32) {
        __syncthreads();
        *(half8*)&sB[srow * 40 + scol] = pB0;
        *(half8*)&sB[(srow + 64) * 40 + scol] = pB1;
        __syncthreads();
        if (k0 + 32 < NK * HID) {
            pB0 = *(const half8*)(W + woff0 + k0 + 32);
            pB1 = *(const half8*)(W + woff1 + k0 + 32);
        }
        int kq = quad * 8;
        half8 a = *(const half8*)&uA[(wy * 16 + ln) * UA_STRIDE + k0 + kq];
        half8 b[4];
#pragma unroll
        for (int j = 0; j < 4; ++j)
            b[j] = *(const half8*)&sB[(wx * 64 + j * 16 + ln) * 40 + kq];
#pragma unroll
        for (int j = 0; j < 4; ++j)
            acc[j] = __builtin_amdgcn_mfma_f32_16x16x32_f16(a, b[j], acc[j], 0, 0, 0);
    }

    // epilogue: C/D layout col = lane&15, row = quad*4 + reg
#pragma unroll
    for (int j = 0; j < 4; ++j) {
        int gc = wx * 64 + j * 16 + ln;
#pragma unroll
        for (int r = 0; r < 4; ++r) {
            int gr = bm + wy * 16 + quad * 4 + r;
            if (gr < N_NODES) C16[(size_t)gr * HID + gc] = (_Float16)acc[j][r];
        }
    }
    // BN stats (rows beyond N_NODES contributed zeros)
#pragma unroll
    for (int j = 0; j < 4; ++j) {
        float s = 0.f, q = 0.f;
#pragma unroll
        for (int r = 0; r < 4; ++r) { float v = acc[j][r]; s += v; q += v * v; }
        s += __shfl_xor(s, 16); s += __shfl_xor(s, 32);
        q += __shfl_xor(q, 16); q += __shfl_xor(q, 32);
        if (quad == 0) {
            atomicAdd(&bsum[wx * 64 + j * 16 + ln], s);
            atomicAdd(&bsq[wx * 64 + j * 16 + ln], q);
        }
    }
    __syncthreads();
    float* slice = bnsum + (blockIdx.x & (NSLICE - 1)) * (2 * HID);
    if (tid < HID) {
        atomicAdd(&slice[tid],       bsum[tid]);
        atomicAdd(&slice[HID + tid], bsq[tid]);
    }
}

// ------- BN apply (fused scale/shift) + ReLU + residual, all-fp16 h
__global__ void bn_apply_kernel(half4v* __restrict__ h16,
                                const half4v* __restrict__ agg16,
                                const float* __restrict__ sc_sh) {
    int idx = blockIdx.x * blockDim.x + threadIdx.x;
    if (idx >= N_NODES * HID / 4) return;
    int c = (idx & 31) * 4;
    half4v a = agg16[idx];
    half4v hv = h16[idx];
    half4v o16;
#pragma unroll
    for (int j = 0; j < 4; ++j) {
        float hn = (float)a[j] * sc_sh[c + j] + sc_sh[HID + c + j];
        o16[j] = (_Float16)((float)hv[j] + fmaxf(hn, 0.f));
    }
    h16[idx] = o16;
}

// -------------------------------------------- fused readout + 3-layer MLP
// 1024 threads/block: 8 row-groups x 128 channels (round-9 winner).
__global__ __launch_bounds__(1024) void readout_mlp_kernel(const _Float16* __restrict__ h16,
                                                           const int* __restrict__ batch,
                                                           const float* __restrict__ w0, const float* __restrict__ b0,
                                                           const float* __restrict__ w1, const float* __restrict__ b1,
                                                           const float* __restrict__ w2, const float* __restrict__ b2,
                                                           float* __restrict__ out) {
    __shared__ float part[8][128];
    __shared__ float hg[128];
    __shared__ float z0[64];
    __shared__ float z1[32];
    __shared__ int range[2];
    int g = blockIdx.x;
    int tid = threadIdx.x;
    if (tid == 0) {
        int lo = 0, hi = N_NODES;
        while (lo < hi) { int mid = (lo + hi) >> 1; if (batch[mid] < g) lo = mid + 1; else hi = mid; }
        range[0] = lo;
        hi = N_NODES;
        while (lo < hi) { int mid = (lo + hi) >> 1; if (batch[mid] < g + 1) lo = mid + 1; else hi = mid; }
        range[1] = lo;
    }
    __syncthreads();
    int lo = range[0], hi = range[1];
    int rg = tid >> 7;            // row-group 0..7
    int ch = tid & 127;           // channel
    float s0 = 0.f, s1 = 0.f, s2 = 0.f, s3 = 0.f;
    int n = lo + rg;
    for (; n + 24 < hi; n += 32) {
        s0 += (float)h16[(size_t)n * HID + ch];
        s1 += (float)h16[(size_t)(n + 8) * HID + ch];
        s2 += (float)h16[(size_t)(n + 16) * HID + ch];
        s3 += (float)h16[(size_t)(n + 24) * HID + ch];
    }
    for (; n < hi; n += 8) s0 += (float)h16[(size_t)n * HID + ch];
    part[rg][ch] = (s0 + s1) + (s2 + s3);
    __syncthreads();
    if (tid < 128) {
        float s = 0.f;
#pragma unroll
        for (int r = 0; r < 8; ++r) s += part[r][tid];
        int cnt = hi - lo; if (cnt < 1) cnt = 1;
        hg[tid] = s / (float)cnt;
    }
    __syncthreads();
    if (tid < 64) {
        float a = b0[tid];
        for (int i = 0; i < 128; ++i) a += hg[i] * w0[tid * 128 + i];
        z0[tid] = fmaxf(a, 0.f);
    }
    __syncthreads();
    if (tid < 32) {
        float a = b1[tid];
        for (int i = 0; i < 64; ++i) a += z0[i] * w1[tid * 64 + i];
        z1[tid] = fmaxf(a, 0.f);
    }
    __syncthreads();
    if (tid < 10) {
        float a = b2[tid];
        for (int i = 0; i < 32; ++i) a += z1[i] * w2[tid * 32 + i];
        out[g * NC + tid] = a;
    }
}

// ----------------------------------------------------------------- launch
extern "C" void kernel_launch(void* const* d_in, const int* in_sizes, int n_in,
                              void* d_out, int out_size, void* d_ws, size_t ws_size,
                              hipStream_t stream) {
    const float* feature = (const float*)d_in[0];
    const int*   edge    = (const int*)d_in[1];
    const int*   row     = edge;
    const int*   col     = edge + N_EDGES;
    const int*   batch   = (const int*)d_in[2];
    const float* emb_w   = (const float*)d_in[3];
    const float* emb_b   = (const float*)d_in[4];
    const float* fc_w    = (const float*)d_in[5];
    const float* mu      = (const float*)d_in[6];
    const float* isig    = (const float*)d_in[7];
    const float* gamma   = (const float*)d_in[8];
    const float* beta    = (const float*)d_in[9];
    const float* pp_w    = (const float*)d_in[10];
    const float* pp_b    = (const float*)d_in[11];
    const float* mw0     = (const float*)d_in[12];
    const float* mb0     = (const float*)d_in[13];
    const float* mw1     = (const float*)d_in[14];
    const float* mb1     = (const float*)d_in[15];
    const float* mw2     = (const float*)d_in[16];
    const float* mb2     = (const float*)d_in[17];
    float* out = (float*)d_out;

    // workspace carve-up (256B aligned) — u eliminated by the fusion.
    char* ws = (char*)d_ws;
    size_t off = 0;
    auto carve = [&](size_t bytes) { size_t o = off; off = (off + bytes + 255) & ~(size_t)255; return o; };
    _Float16* h16   = (_Float16*)(ws + carve((size_t)N_NODES * HID * 2));
    _Float16* agg16 = (_Float16*)(ws + carve((size_t)N_NODES * HID * 2));
    int* esrc       = (int*)(ws + carve((size_t)N_EDGES * 4));
    _Float16* w2t   = (_Float16*)(ws + carve((size_t)NL * HID * NK * HID * 2));
    _Float16* f16   = (_Float16*)(ws + carve((size_t)N_NODES * HID * 2));
    _Float16* e16   = (_Float16*)(ws + carve((size_t)HID * HID * 2));
    int* degr       = (int*)(ws + carve((size_t)N_NODES * 4));
    int* degc       = (int*)(ws + carve((size_t)N_NODES * 4));
    int* csr_off    = (int*)(ws + carve((size_t)(N_NODES + 1) * 4));
    int* cursor     = (int*)(ws + carve((size_t)N_NODES * 4));
    int* blocksum   = (int*)(ws + carve((size_t)SCAN_G * 4));
    unsigned* pr    = (unsigned*)(ws + carve((size_t)H_CHK * PKW * 4));
    unsigned* pc    = (unsigned*)(ws + carve((size_t)H_CHK * PKW * 4));
    float* bnsum    = (float*)(ws + carve((size_t)NL * NSLICE * 2 * HID * 4));
    float* bnfin    = (float*)(ws + carve((size_t)NL * 2 * HID * 4));
    (void)ws_size; (void)in_sizes; (void)n_in; (void)out_size;

    hipMemsetAsync(bnsum, 0, (size_t)NL * NSLICE * 2 * HID * 4, stream);

    hist_lds_kernel<<<dim3(H_CHK, 2), 256, 0, stream>>>(row, col, pr, pc);
    hist_reduce_kernel<<<(PKW + 255) / 256, 256, 0, stream>>>(pr, pc, degr, degc);
    scan1_kernel<<<SCAN_G, 256, 0, stream>>>(degc, csr_off, blocksum);
    scan2_kernel<<<1, 256, 0, stream>>>(blocksum);
    scan3_kernel<<<SCAN_G, 256, 0, stream>>>(blocksum, csr_off, cursor);
    fill_src_kernel<<<FP_CHK * 8, 256, 0, stream>>>(col, row, cursor, esrc);

    prep16_kernel<<<((N_NODES * HID + HID * HID) / 4 + NL * NK * HID * HID + 255) / 256,
                    256, 0, stream>>>(
        (const float4*)feature, N_NODES * HID / 4, (const float4*)emb_w, HID * HID / 4,
        (half4v*)f16, (half4v*)e16, fc_w, w2t);

    // h16 = feature @ emb_w^T + emb_b
    gemm_f16_kernel<<<(N_NODES + 63) / 64, 256, 0, stream>>>(
        f16, e16, emb_b, h16, N_NODES, HID);

    for (int l = 0; l < NL; ++l) {
        agg_gemm_kernel<<<(N_NODES + AG_BM - 1) / AG_BM, 256, 0, stream>>>(
            csr_off, esrc, degr, degc, (const char*)h16,
            w2t + (size_t)l * HID * NK * HID, agg16,
            bnsum + (size_t)l * NSLICE * 2 * HID,
            pp_w + l * 4, pp_b + l * 2, mu + l * 6, isig + l * 6);
        bn_finalize_kernel<<<1, 128, 0, stream>>>(
            bnsum + (size_t)l * NSLICE * 2 * HID, gamma + l * HID, beta + l * HID,
            bnfin + l * 2 * HID);
        bn_apply_kernel<<<(N_NODES * HID / 4 + 255) / 256, 256, 0, stream>>>(
            (half4v*)h16, (const half4v*)agg16, bnfin + l * 2 * HID);
    }

    readout_mlp_kernel<<<N_GRAPHS, 1024, 0, stream>>>(h16, batch, mw0, mb0, mw1, mb1, mw2, mb2, out);
}

// Round 14
// 451.639 us; speedup vs baseline: 1.1914x; 1.1914x over previous
//
#include <hip/hip_runtime.h>
#include <hip/hip_bf16.h>

#define N_NODES 50000
#define N_EDGES 800000
#define N_GRAPHS 128
#define HID 128
#define NK 3
#define NL 4
#define NC 10
#define BN_EPS 1e-5f
#define SCAN_G ((N_NODES + 255) / 256)
#define NSLICE 32

// fill_src bucketed scatter
#define BKT_SZ 8192
#define NBKT 7                    // ceil(50000/8192)
#define FP_CHK 256
#define FP_E (N_EDGES / FP_CHK)   // 3125

// full-range packed-LDS histogram
#define H_CHK 64
#define H_E (N_EDGES / H_CHK)     // 12500 edges/chunk  (<= 65535 -> fits u16)
#define PKW (N_NODES / 2)         // 25000 packed words = 100 KB LDS

typedef __attribute__((ext_vector_type(8))) _Float16 half8;
typedef __attribute__((ext_vector_type(4))) float floatx4;
typedef __attribute__((ext_vector_type(2))) float float2v;
typedef __attribute__((ext_vector_type(2))) _Float16 half2v;
typedef __attribute__((ext_vector_type(4))) _Float16 half4v;

__device__ __forceinline__ float tanh_fast(float x) {
    float ax = fabsf(x);
    float t = __expf(-2.0f * ax);
    float r = (1.0f - t) / (1.0f + t);
    return copysignf(r, x);
}

// ------- degree histogram: full node range in 100 KB LDS, u16-packed counts.
__global__ __launch_bounds__(256) void hist_lds_kernel(const int* __restrict__ row,
                                                       const int* __restrict__ col,
                                                       unsigned* __restrict__ pr,
                                                       unsigned* __restrict__ pc) {
    __shared__ unsigned hh[PKW];
    int tid = threadIdx.x;
    const int4* arr = (const int4*)(blockIdx.y ? col : row);
    unsigned* out = (blockIdx.y ? pc : pr) + (size_t)blockIdx.x * PKW;
    uint4* hh4 = (uint4*)hh;
    const uint4 z4 = {0u, 0u, 0u, 0u};
    for (int i = tid; i < PKW / 4; i += 256) hh4[i] = z4;
    __syncthreads();
    int base4 = blockIdx.x * (H_E / 4);
    for (int i = tid; i < H_E / 4; i += 256) {
        int4 v = arr[base4 + i];
        atomicAdd(&hh[v.x >> 1], 1u << ((v.x & 1) << 4));
        atomicAdd(&hh[v.y >> 1], 1u << ((v.y & 1) << 4));
        atomicAdd(&hh[v.z >> 1], 1u << ((v.z & 1) << 4));
        atomicAdd(&hh[v.w >> 1], 1u << ((v.w & 1) << 4));
    }
    __syncthreads();
    uint4* out4 = (uint4*)out;
    for (int i = tid; i < PKW / 4; i += 256) out4[i] = hh4[i];
}

// reduce packed partials -> degr/degc (unpack BEFORE summing)
__global__ __launch_bounds__(256) void hist_reduce_kernel(const unsigned* __restrict__ pr,
                                                          const unsigned* __restrict__ pc,
                                                          int* __restrict__ degr,
                                                          int* __restrict__ degc) {
    int w = blockIdx.x * 256 + threadIdx.x;
    if (w >= PKW) return;
    unsigned rlo = 0, rhi = 0, clo = 0, chi = 0;
    for (int ch = 0; ch < H_CHK; ++ch) {
        unsigned a = pr[(size_t)ch * PKW + w];
        unsigned b = pc[(size_t)ch * PKW + w];
        rlo += a & 0xFFFFu; rhi += a >> 16;
        clo += b & 0xFFFFu; chi += b >> 16;
    }
    ((int2*)degr)[w] = make_int2((int)rlo, (int)rhi);
    ((int2*)degc)[w] = make_int2((int)clo, (int)chi);
}

// ------------------------------------------------ hierarchical scan (3 kernels)
__global__ __launch_bounds__(256) void scan1_kernel(const int* __restrict__ degc,
                                                    int* __restrict__ csr_off,
                                                    int* __restrict__ blocksum) {
    __shared__ int buf[256];
    int tid = threadIdx.x;
    int i = blockIdx.x * 256 + tid;
    int v = (i < N_NODES) ? degc[i] : 0;
    buf[tid] = v;
    __syncthreads();
    for (int d = 1; d < 256; d <<= 1) {
        int t = (tid >= d) ? buf[tid - d] : 0;
        __syncthreads();
        buf[tid] += t;
        __syncthreads();
    }
    if (i < N_NODES) csr_off[i] = buf[tid] - v;
    if (tid == 255) blocksum[blockIdx.x] = buf[255];
}

__global__ __launch_bounds__(256) void scan2_kernel(int* __restrict__ blocksum) {
    __shared__ int buf[256];
    int tid = threadIdx.x;
    int v = (tid < SCAN_G) ? blocksum[tid] : 0;
    buf[tid] = v;
    __syncthreads();
    for (int d = 1; d < 256; d <<= 1) {
        int t = (tid >= d) ? buf[tid - d] : 0;
        __syncthreads();
        buf[tid] += t;
        __syncthreads();
    }
    if (tid < SCAN_G) blocksum[tid] = buf[tid] - v;   // exclusive, in place
}

__global__ __launch_bounds__(256) void scan3_kernel(const int* __restrict__ blocksum,
                                                    int* __restrict__ csr_off,
                                                    int* __restrict__ cursor) {
    int i = blockIdx.x * 256 + threadIdx.x;
    if (i < N_NODES) {
        int v = csr_off[i] + blocksum[blockIdx.x];
        csr_off[i] = v;
        cursor[i] = v;
    }
    if (i == 0) csr_off[N_NODES] = N_EDGES;
}

// ---------- counting-sort scatter: 4-B records (src node id only).
// px = rsqrt(degr[src]+1) is a pure function of src -> recomputed in
// aggregate from the L2-resident degr table.
__global__ __launch_bounds__(256) void fill_src_kernel(const int* __restrict__ col,
                                                       const int* __restrict__ row,
                                                       int* __restrict__ cursor,
                                                       int* __restrict__ esrc) {
    int bkt = blockIdx.x & 7;
    if (bkt >= NBKT) return;          // bucket 7 is empty padding
    int chunk = blockIdx.x >> 3;
    int base = bkt * BKT_SZ;
    int e0 = chunk * FP_E;
    for (int e = e0 + threadIdx.x; e < e0 + FP_E; e += 256) {
        unsigned c = (unsigned)(col[e] - base);
        if (c < BKT_SZ) {
            int pos = atomicAdd(&cursor[base + (int)c], 1);
            esrc[pos] = row[e];
        }
    }
}

// --------------------- fp32->fp16 converts + fc_w transpose, one dispatch.
__global__ void prep16_kernel(const float4* __restrict__ a, int n4a,
                              const float4* __restrict__ b, int n4b,
                              half4v* __restrict__ da, half4v* __restrict__ db,
                              const float* __restrict__ fc_w,
                              _Float16* __restrict__ w2t) {
    int i = blockIdx.x * blockDim.x + threadIdx.x;
    if (i < n4a + n4b) {
        const float4* src; half4v* dst; int idx;
        if (i < n4a) { src = a; dst = da; idx = i; }
        else { src = b; dst = db; idx = i - n4a; }
        float4 f = src[idx];
        half4v o;
        o.x = (_Float16)f.x; o.y = (_Float16)f.y; o.z = (_Float16)f.z; o.w = (_Float16)f.w;
        dst[idx] = o;
        return;
    }
    int idx = i - (n4a + n4b);
    if (idx >= NL * NK * HID * HID) return;
    int ii = idx & (HID - 1);
    int j = (idx >> 7) & (HID - 1);
    int kl = idx >> 14;          // l*3 + k
    int k = kl % 3;
    int l = kl / 3;
    w2t[((size_t)(l * HID + j)) * (NK * HID) + k * HID + ii] = (_Float16)fc_w[idx];
}

// -------------------------------------------------- fp16 MFMA GEMM, BM=64
// (round-11 winner: 64x128 tile, 4 waves, 782 blocks -> not grid-starved)
__global__ __launch_bounds__(256) void gemm_f16_kernel(
        const _Float16* __restrict__ A, const _Float16* __restrict__ W,
        const float* __restrict__ bias, _Float16* __restrict__ C16,
        float* __restrict__ bnsum, int M, int Kd) {
    __shared__ _Float16 sA[64 * 40], sB[128 * 40];    // stride 40 halfs
    __shared__ float bsum[HID], bsq[HID];
    int tid = threadIdx.x;
    if (bnsum && tid < HID) { bsum[tid] = 0.f; bsq[tid] = 0.f; }
    int bm = blockIdx.x * 64;
    int wave = tid >> 6, lane = tid & 63;
    int ln = lane & 15, quad = lane >> 4;
    int wy = wave >> 1, wx = wave & 1;
    int srow = tid >> 2, scol = (tid & 3) << 3;
    floatx4 acc[2][4] = {};
    const half8 zv = {0, 0, 0, 0, 0, 0, 0, 0};

    half8 pA, pB[2];
    bool av0 = (bm + srow) < M;
    const size_t aoff0 = (size_t)(bm + srow) * Kd + scol;
    const size_t woff0 = (size_t)srow * Kd + scol;
    const size_t woff1 = (size_t)(srow + 64) * Kd + scol;

#define LOAD_TILE(K0)                                                          \
    do {                                                                       \
        pB[0] = *(const half8*)(W + woff0 + (K0));                             \
        pB[1] = *(const half8*)(W + woff1 + (K0));                             \
        pA = av0 ? *(const half8*)(A + aoff0 + (K0)) : zv;                     \
    } while (0)

    LOAD_TILE(0);
    for (int k0 = 0; k0 < Kd; k0 += 32) {
        __syncthreads();
        *(half8*)&sA[srow * 40 + scol] = pA;
        *(half8*)&sB[srow * 40 + scol] = pB[0];
        *(half8*)&sB[(srow + 64) * 40 + scol] = pB[1];
        __syncthreads();
        if (k0 + 32 < Kd) LOAD_TILE(k0 + 32);   // overlaps with MFMA below
        half8 a[2], b[4];
        int kq = quad * 8;
#pragma unroll
        for (int i = 0; i < 2; ++i)
            a[i] = *(const half8*)&sA[(wy * 32 + i * 16 + ln) * 40 + kq];
#pragma unroll
        for (int j = 0; j < 4; ++j)
            b[j] = *(const half8*)&sB[(wx * 64 + j * 16 + ln) * 40 + kq];
#pragma unroll
        for (int i = 0; i < 2; ++i)
#pragma unroll
            for (int j = 0; j < 4; ++j)
                acc[i][j] = __builtin_amdgcn_mfma_f32_16x16x32_f16(a[i], b[j], acc[i][j], 0, 0, 0);
    }
#undef LOAD_TILE

    // epilogue: C/D layout col = lane&15, row = quad*4 + reg
#pragma unroll
    for (int j = 0; j < 4; ++j) {
        int gc = wx * 64 + j * 16 + ln;
        float bv = bias ? bias[gc] : 0.f;
#pragma unroll
        for (int i = 0; i < 2; ++i) {
#pragma unroll
            for (int r = 0; r < 4; ++r) {
                int gr = bm + wy * 32 + i * 16 + quad * 4 + r;
                if (gr < M) C16[(size_t)gr * HID + gc] = (_Float16)(acc[i][j][r] + bv);
            }
        }
    }
    if (bnsum) {
        // rows beyond M accumulated zeros (A loaded as 0, no bias) -> safe
#pragma unroll
        for (int j = 0; j < 4; ++j) {
            float s = 0.f, q = 0.f;
#pragma unroll
            for (int i = 0; i < 2; ++i)
#pragma unroll
                for (int r = 0; r < 4; ++r) { float v = acc[i][j][r]; s += v; q += v * v; }
            s += __shfl_xor(s, 16); s += __shfl_xor(s, 32);
            q += __shfl_xor(q, 16); q += __shfl_xor(q, 32);
            if (quad == 0) {
                atomicAdd(&bsum[wx * 64 + j * 16 + ln], s);
                atomicAdd(&bsq[wx * 64 + j * 16 + ln], q);
            }
        }
        __syncthreads();
        float* slice = bnsum + (blockIdx.x & (NSLICE - 1)) * (2 * HID);
        if (tid < HID) {
            atomicAdd(&slice[tid],       bsum[tid]);
            atomicAdd(&slice[HID + tid], bsq[tid]);
        }
    }
}

// ---- reduce BN slices -> fused scale/shift (one tiny block per layer)
__global__ __launch_bounds__(128) void bn_finalize_kernel(const float* __restrict__ slices,
                                                          const float* __restrict__ gamma,
                                                          const float* __restrict__ beta,
                                                          float* __restrict__ sc_sh) {
    int t = threadIdx.x;   // channel
    float s = 0.f, q = 0.f;
    for (int sl = 0; sl < NSLICE; ++sl) {
        s += slices[sl * (2 * HID) + t];
        q += slices[sl * (2 * HID) + HID + t];
    }
    const float invN = 1.0f / (float)N_NODES;
    float mean = s * invN;
    float var = q * invN - mean * mean;
    float scale = gamma[t] * rsqrtf(var + BN_EPS);
    sc_sh[t] = scale;
    sc_sh[HID + t] = beta[t] - mean * scale;
}

// ----------- CSR aggregation: per-node serial, 32-lane sub-groups + inline
// edge-weight recompute. esrc holds only the src node id; px is recomputed
// from the L2-resident degr table (identical fp32 sequence as before).
__global__ __launch_bounds__(256) void aggregate_kernel(const int* __restrict__ csr_off,
                                                        const int* __restrict__ esrc,
                                                        const int* __restrict__ degr,
                                                        const int* __restrict__ degc,
                                                        const char* __restrict__ h16,
                                                        _Float16* __restrict__ u,
                                                        const float* __restrict__ pw,
                                                        const float* __restrict__ pb,
                                                        const float* __restrict__ mu,
                                                        const float* __restrict__ isg) {
    int wave = threadIdx.x >> 6;
    int lane = threadIdx.x & 63;
    int sub = lane >> 5;          // which node in the wave
    int sl = lane & 31;           // lane within 32-group
    int base = sub << 5;          // shfl source base
    int n = blockIdx.x * 8 + wave * 2 + sub;
    if (n >= N_NODES) return;
    int beg = csr_off[n], end = csr_off[n + 1];
    float py = rsqrtf((float)degc[n] + 1.0f);
    float pw0 = pw[0], pw1 = pw[1], pw2 = pw[2], pw3 = pw[3];
    float pb0 = pb[0], pb1 = pb[1];
    float m00 = mu[0], m01 = mu[1], m10 = mu[2], m11 = mu[3], m20 = mu[4], m21 = mu[5];
    float s00 = isg[0], s01 = isg[1], s10 = isg[2], s11 = isg[3], s20 = isg[4], s21 = isg[5];
    const char* hb = h16 + sl * 8;
    floatx4 a0 = {0.f, 0.f, 0.f, 0.f}, a1 = a0, a2 = a0;

    for (int chunk = beg; chunk < end; chunk += 32) {
        int ce = chunk + sl;
        int rsrc = (ce < end) ? esrc[ce] : 0;
        float px = rsqrtf((float)degr[rsrc] + 1.0f);
        int roff = rsrc << 8;     // byte offset into fp16 h row (256 B)
        float ps0 = tanh_fast(px * pw0 + py * pw1 + pb0);
        float ps1 = tanh_fast(px * pw2 + py * pw3 + pb1);
        float d0 = ps0 - m00, d1 = ps1 - m01;
        float w0 = __expf(-0.5f * (d0 * d0 * s00 * s00 + d1 * d1 * s01 * s01));
        d0 = ps0 - m10; d1 = ps1 - m11;
        float w1 = __expf(-0.5f * (d0 * d0 * s10 * s10 + d1 * d1 * s11 * s11));
        d0 = ps0 - m20; d1 = ps1 - m21;
        float w2 = __expf(-0.5f * (d0 * d0 * s20 * s20 + d1 * d1 * s21 * s21));
        int m = end - chunk; if (m > 32) m = 32;
        int t = 0;
        for (; t + 8 <= m; t += 8) {
            int ro[8];
#pragma unroll
            for (int s = 0; s < 8; ++s) ro[s] = __shfl(roff, base + t + s);
            half4v hv[8];
#pragma unroll
            for (int s = 0; s < 8; ++s) hv[s] = *(const half4v*)(hb + (unsigned)ro[s]);
#pragma unroll
            for (int s = 0; s < 8; ++s) {
                float wx = __shfl(w0, base + t + s);
                float wy = __shfl(w1, base + t + s);
                float wz = __shfl(w2, base + t + s);
                floatx4 hf = {(float)hv[s].x, (float)hv[s].y, (float)hv[s].z, (float)hv[s].w};
                a0 += wx * hf;
                a1 += wy * hf;
                a2 += wz * hf;
            }
        }
        for (; t < m; ++t) {
            int ro = __shfl(roff, base + t);
            float wx = __shfl(w0, base + t);
            float wy = __shfl(w1, base + t);
            float wz = __shfl(w2, base + t);
            half4v hv = *(const half4v*)(hb + (unsigned)ro);
            floatx4 hf = {(float)hv.x, (float)hv.y, (float)hv.z, (float)hv.w};
            a0 += wx * hf;
            a1 += wy * hf;
            a2 += wz * hf;
        }
    }
    size_t b = (size_t)n * 384 + sl * 4;
    half4v o0, o1, o2;
    o0.x = (_Float16)a0.x; o0.y = (_Float16)a0.y; o0.z = (_Float16)a0.z; o0.w = (_Float16)a0.w;
    o1.x = (_Float16)a1.x; o1.y = (_Float16)a1.y; o1.z = (_Float16)a1.z; o1.w = (_Float16)a1.w;
    o2.x = (_Float16)a2.x; o2.y = (_Float16)a2.y; o2.z = (_Float16)a2.z; o2.w = (_Float16)a2.w;
    *(half4v*)(u + b)       = o0;
    *(half4v*)(u + b + 128) = o1;
    *(half4v*)(u + b + 256) = o2;
}

// ------- BN apply (fused scale/shift) + ReLU + residual, all-fp16 h
__global__ void bn_apply_kernel(half4v* __restrict__ h16,
                                const half4v* __restrict__ agg16,
                                const float* __restrict__ sc_sh) {
    int idx = blockIdx.x * blockDim.x + threadIdx.x;
    if (idx >= N_NODES * HID / 4) return;
    int c = (idx & 31) * 4;
    half4v a = agg16[idx];
    half4v hv = h16[idx];
    half4v o16;
#pragma unroll
    for (int j = 0; j < 4; ++j) {
        float hn = (float)a[j] * sc_sh[c + j] + sc_sh[HID + c + j];
        o16[j] = (_Float16)((float)hv[j] + fmaxf(hn, 0.f));
    }
    h16[idx] = o16;
}

// -------------------------------------------- fused readout + 3-layer MLP
// 1024 threads/block: 8 row-groups x 128 channels (round-9 winner).
__global__ __launch_bounds__(1024) void readout_mlp_kernel(const _Float16* __restrict__ h16,
                                                           const int* __restrict__ batch,
                                                           const float* __restrict__ w0, const float* __restrict__ b0,
                                                           const float* __restrict__ w1, const float* __restrict__ b1,
                                                           const float* __restrict__ w2, const float* __restrict__ b2,
                                                           float* __restrict__ out) {
    __shared__ float part[8][128];
    __shared__ float hg[128];
    __shared__ float z0[64];
    __shared__ float z1[32];
    __shared__ int range[2];
    int g = blockIdx.x;
    int tid = threadIdx.x;
    if (tid == 0) {
        int lo = 0, hi = N_NODES;
        while (lo < hi) { int mid = (lo + hi) >> 1; if (batch[mid] < g) lo = mid + 1; else hi = mid; }
        range[0] = lo;
        hi = N_NODES;
        while (lo < hi) { int mid = (lo + hi) >> 1; if (batch[mid] < g + 1) lo = mid + 1; else hi = mid; }
        range[1] = lo;
    }
    __syncthreads();
    int lo = range[0], hi = range[1];
    int rg = tid >> 7;            // row-group 0..7
    int ch = tid & 127;           // channel
    float s0 = 0.f, s1 = 0.f, s2 = 0.f, s3 = 0.f;
    int n = lo + rg;
    for (; n + 24 < hi; n += 32) {
        s0 += (float)h16[(size_t)n * HID + ch];
        s1 += (float)h16[(size_t)(n + 8) * HID + ch];
        s2 += (float)h16[(size_t)(n + 16) * HID + ch];
        s3 += (float)h16[(size_t)(n + 24) * HID + ch];
    }
    for (; n < hi; n += 8) s0 += (float)h16[(size_t)n * HID + ch];
    part[rg][ch] = (s0 + s1) + (s2 + s3);
    __syncthreads();
    if (tid < 128) {
        float s = 0.f;
#pragma unroll
        for (int r = 0; r < 8; ++r) s += part[r][tid];
        int cnt = hi - lo; if (cnt < 1) cnt = 1;
        hg[tid] = s / (float)cnt;
    }
    __syncthreads();
    if (tid < 64) {
        float a = b0[tid];
        for (int i = 0; i < 128; ++i) a += hg[i] * w0[tid * 128 + i];
        z0[tid] = fmaxf(a, 0.f);
    }
    __syncthreads();
    if (tid < 32) {
        float a = b1[tid];
        for (int i = 0; i < 64; ++i) a += z0[i] * w1[tid * 64 + i];
        z1[tid] = fmaxf(a, 0.f);
    }
    __syncthreads();
    if (tid < 10) {
        float a = b2[tid];
        for (int i = 0; i < 32; ++i) a += z1[i] * w2[tid * 32 + i];
        out[g * NC + tid] = a;
    }
}

// ----------------------------------------------------------------- launch
extern "C" void kernel_launch(void* const* d_in, const int* in_sizes, int n_in,
                              void* d_out, int out_size, void* d_ws, size_t ws_size,
                              hipStream_t stream) {
    const float* feature = (const float*)d_in[0];
    const int*   edge    = (const int*)d_in[1];
    const int*   row     = edge;
    const int*   col     = edge + N_EDGES;
    const int*   batch   = (const int*)d_in[2];
    const float* emb_w   = (const float*)d_in[3];
    const float* emb_b   = (const float*)d_in[4];
    const float* fc_w    = (const float*)d_in[5];
    const float* mu      = (const float*)d_in[6];
    const float* isig    = (const float*)d_in[7];
    const float* gamma   = (const float*)d_in[8];
    const float* beta    = (const float*)d_in[9];
    const float* pp_w    = (const float*)d_in[10];
    const float* pp_b    = (const float*)d_in[11];
    const float* mw0     = (const float*)d_in[12];
    const float* mb0     = (const float*)d_in[13];
    const float* mw1     = (const float*)d_in[14];
    const float* mb1     = (const float*)d_in[15];
    const float* mw2     = (const float*)d_in[16];
    const float* mb2     = (const float*)d_in[17];
    float* out = (float*)d_out;

    // workspace carve-up (256B aligned)
    char* ws = (char*)d_ws;
    size_t off = 0;
    auto carve = [&](size_t bytes) { size_t o = off; off = (off + bytes + 255) & ~(size_t)255; return o; };
    _Float16* h16   = (_Float16*)(ws + carve((size_t)N_NODES * HID * 2));
    _Float16* u     = (_Float16*)(ws + carve((size_t)N_NODES * NK * HID * 2));
    _Float16* agg16 = (_Float16*)(ws + carve((size_t)N_NODES * HID * 2));
    int* esrc       = (int*)(ws + carve((size_t)N_EDGES * 4));
    _Float16* w2t   = (_Float16*)(ws + carve((size_t)NL * HID * NK * HID * 2));
    _Float16* f16   = (_Float16*)(ws + carve((size_t)N_NODES * HID * 2));
    _Float16* e16   = (_Float16*)(ws + carve((size_t)HID * HID * 2));
    int* degr       = (int*)(ws + carve((size_t)N_NODES * 4));
    int* degc       = (int*)(ws + carve((size_t)N_NODES * 4));
    int* csr_off    = (int*)(ws + carve((size_t)(N_NODES + 1) * 4));
    int* cursor     = (int*)(ws + carve((size_t)N_NODES * 4));
    int* blocksum   = (int*)(ws + carve((size_t)SCAN_G * 4));
    unsigned* pr    = (unsigned*)(ws + carve((size_t)H_CHK * PKW * 4));
    unsigned* pc    = (unsigned*)(ws + carve((size_t)H_CHK * PKW * 4));
    float* bnsum    = (float*)(ws + carve((size_t)NL * NSLICE * 2 * HID * 4));
    float* bnfin    = (float*)(ws + carve((size_t)NL * 2 * HID * 4));
    (void)ws_size; (void)in_sizes; (void)n_in; (void)out_size;

    hipMemsetAsync(bnsum, 0, (size_t)NL * NSLICE * 2 * HID * 4, stream);

    hist_lds_kernel<<<dim3(H_CHK, 2), 256, 0, stream>>>(row, col, pr, pc);
    hist_reduce_kernel<<<(PKW + 255) / 256, 256, 0, stream>>>(pr, pc, degr, degc);
    scan1_kernel<<<SCAN_G, 256, 0, stream>>>(degc, csr_off, blocksum);
    scan2_kernel<<<1, 256, 0, stream>>>(blocksum);
    scan3_kernel<<<SCAN_G, 256, 0, stream>>>(blocksum, csr_off, cursor);
    fill_src_kernel<<<FP_CHK * 8, 256, 0, stream>>>(col, row, cursor, esrc);

    prep16_kernel<<<((N_NODES * HID + HID * HID) / 4 + NL * NK * HID * HID + 255) / 256,
                    256, 0, stream>>>(
        (const float4*)feature, N_NODES * HID / 4, (const float4*)emb_w, HID * HID / 4,
        (half4v*)f16, (half4v*)e16, fc_w, w2t);

    // h16 = feature @ emb_w^T + emb_b
    gemm_f16_kernel<<<(N_NODES + 63) / 64, 256, 0, stream>>>(
        f16, e16, emb_b, h16, nullptr, N_NODES, HID);

    for (int l = 0; l < NL; ++l) {
        aggregate_kernel<<<(N_NODES + 7) / 8, 256, 0, stream>>>(
            csr_off, esrc, degr, degc, (const char*)h16, u,
            pp_w + l * 4, pp_b + l * 2, mu + l * 6, isig + l * 6);
        gemm_f16_kernel<<<(N_NODES + 63) / 64, 256, 0, stream>>>(
            u, w2t + (size_t)l * HID * NK * HID, nullptr, agg16,
            bnsum + (size_t)l * NSLICE * 2 * HID, N_NODES, NK * HID);
        bn_finalize_kernel<<<1, 128, 0, stream>>>(
            bnsum + (size_t)l * NSLICE * 2 * HID, gamma + l * HID, beta + l * HID,
            bnfin + l * 2 * HID);
        bn_apply_kernel<<<(N_NODES * HID / 4 + 255) / 256, 256, 0, stream>>>(
            (half4v*)h16, (const half4v*)agg16, bnfin + l * 2 * HID);
    }

    readout_mlp_kernel<<<N_GRAPHS, 1024, 0, stream>>>(h16, batch, mw0, mb0, mw1, mb1, mw2, mb2, out);
}

// Round 15
// 434.748 us; speedup vs baseline: 1.2377x; 1.0389x over previous
//
#include <hip/hip_runtime.h>
#include <hip/hip_bf16.h>

#define N_NODES 50000
#define N_EDGES 800000
#define N_GRAPHS 128
#define HID 128
#define NK 3
#define NL 4
#define NC 10
#define BN_EPS 1e-5f
#define SCAN_G ((N_NODES + 255) / 256)
#define NSLICE 32

// fill_src bucketed scatter
#define BKT_SZ 8192
#define NBKT 7                    // ceil(50000/8192)
#define FP_CHK 256
#define FP_E (N_EDGES / FP_CHK)   // 3125

// full-range packed-LDS histogram
#define H_CHK 64
#define H_E (N_EDGES / H_CHK)     // 12500 edges/chunk  (<= 65535 -> fits u16)
#define PKW (N_NODES / 2)         // 25000 packed words = 100 KB LDS

typedef __attribute__((ext_vector_type(8))) _Float16 half8;
typedef __attribute__((ext_vector_type(4))) float floatx4;
typedef __attribute__((ext_vector_type(2))) float float2v;
typedef __attribute__((ext_vector_type(2))) _Float16 half2v;
typedef __attribute__((ext_vector_type(4))) _Float16 half4v;

__device__ __forceinline__ float tanh_fast(float x) {
    float ax = fabsf(x);
    float t = __expf(-2.0f * ax);
    float r = (1.0f - t) / (1.0f + t);
    return copysignf(r, x);
}

// ------- degree histogram: full node range in 100 KB LDS, u16-packed counts.
__global__ __launch_bounds__(256) void hist_lds_kernel(const int* __restrict__ row,
                                                       const int* __restrict__ col,
                                                       unsigned* __restrict__ pr,
                                                       unsigned* __restrict__ pc) {
    __shared__ unsigned hh[PKW];
    int tid = threadIdx.x;
    const int4* arr = (const int4*)(blockIdx.y ? col : row);
    unsigned* out = (blockIdx.y ? pc : pr) + (size_t)blockIdx.x * PKW;
    uint4* hh4 = (uint4*)hh;
    const uint4 z4 = {0u, 0u, 0u, 0u};
    for (int i = tid; i < PKW / 4; i += 256) hh4[i] = z4;
    __syncthreads();
    int base4 = blockIdx.x * (H_E / 4);
    for (int i = tid; i < H_E / 4; i += 256) {
        int4 v = arr[base4 + i];
        atomicAdd(&hh[v.x >> 1], 1u << ((v.x & 1) << 4));
        atomicAdd(&hh[v.y >> 1], 1u << ((v.y & 1) << 4));
        atomicAdd(&hh[v.z >> 1], 1u << ((v.z & 1) << 4));
        atomicAdd(&hh[v.w >> 1], 1u << ((v.w & 1) << 4));
    }
    __syncthreads();
    uint4* out4 = (uint4*)out;
    for (int i = tid; i < PKW / 4; i += 256) out4[i] = hh4[i];
}

// reduce packed partials -> degr/degc (unpack BEFORE summing)
__global__ __launch_bounds__(256) void hist_reduce_kernel(const unsigned* __restrict__ pr,
                                                          const unsigned* __restrict__ pc,
                                                          int* __restrict__ degr,
                                                          int* __restrict__ degc) {
    int w = blockIdx.x * 256 + threadIdx.x;
    if (w >= PKW) return;
    unsigned rlo = 0, rhi = 0, clo = 0, chi = 0;
    for (int ch = 0; ch < H_CHK; ++ch) {
        unsigned a = pr[(size_t)ch * PKW + w];
        unsigned b = pc[(size_t)ch * PKW + w];
        rlo += a & 0xFFFFu; rhi += a >> 16;
        clo += b & 0xFFFFu; chi += b >> 16;
    }
    ((int2*)degr)[w] = make_int2((int)rlo, (int)rhi);
    ((int2*)degc)[w] = make_int2((int)clo, (int)chi);
}

// ------------------------------------------------ hierarchical scan (3 kernels)
__global__ __launch_bounds__(256) void scan1_kernel(const int* __restrict__ degc,
                                                    int* __restrict__ csr_off,
                                                    int* __restrict__ blocksum) {
    __shared__ int buf[256];
    int tid = threadIdx.x;
    int i = blockIdx.x * 256 + tid;
    int v = (i < N_NODES) ? degc[i] : 0;
    buf[tid] = v;
    __syncthreads();
    for (int d = 1; d < 256; d <<= 1) {
        int t = (tid >= d) ? buf[tid - d] : 0;
        __syncthreads();
        buf[tid] += t;
        __syncthreads();
    }
    if (i < N_NODES) csr_off[i] = buf[tid] - v;
    if (tid == 255) blocksum[blockIdx.x] = buf[255];
}

__global__ __launch_bounds__(256) void scan2_kernel(int* __restrict__ blocksum) {
    __shared__ int buf[256];
    int tid = threadIdx.x;
    int v = (tid < SCAN_G) ? blocksum[tid] : 0;
    buf[tid] = v;
    __syncthreads();
    for (int d = 1; d < 256; d <<= 1) {
        int t = (tid >= d) ? buf[tid - d] : 0;
        __syncthreads();
        buf[tid] += t;
        __syncthreads();
    }
    if (tid < SCAN_G) blocksum[tid] = buf[tid] - v;   // exclusive, in place
}

__global__ __launch_bounds__(256) void scan3_kernel(const int* __restrict__ blocksum,
                                                    int* __restrict__ csr_off,
                                                    int* __restrict__ cursor) {
    int i = blockIdx.x * 256 + threadIdx.x;
    if (i < N_NODES) {
        int v = csr_off[i] + blocksum[blockIdx.x];
        csr_off[i] = v;
        cursor[i] = v;
    }
    if (i == 0) csr_off[N_NODES] = N_EDGES;
}

// ---------- counting-sort scatter: 4-B records (src node id only).
__global__ __launch_bounds__(256) void fill_src_kernel(const int* __restrict__ col,
                                                       const int* __restrict__ row,
                                                       int* __restrict__ cursor,
                                                       int* __restrict__ esrc) {
    int bkt = blockIdx.x & 7;
    if (bkt >= NBKT) return;          // bucket 7 is empty padding
    int chunk = blockIdx.x >> 3;
    int base = bkt * BKT_SZ;
    int e0 = chunk * FP_E;
    for (int e = e0 + threadIdx.x; e < e0 + FP_E; e += 256) {
        unsigned c = (unsigned)(col[e] - base);
        if (c < BKT_SZ) {
            int pos = atomicAdd(&cursor[base + (int)c], 1);
            esrc[pos] = row[e];
        }
    }
}

// --------------------- fp32->fp16 converts + fc_w transpose, one dispatch.
__global__ void prep16_kernel(const float4* __restrict__ a, int n4a,
                              const float4* __restrict__ b, int n4b,
                              half4v* __restrict__ da, half4v* __restrict__ db,
                              const float* __restrict__ fc_w,
                              _Float16* __restrict__ w2t) {
    int i = blockIdx.x * blockDim.x + threadIdx.x;
    if (i < n4a + n4b) {
        const float4* src; half4v* dst; int idx;
        if (i < n4a) { src = a; dst = da; idx = i; }
        else { src = b; dst = db; idx = i - n4a; }
        float4 f = src[idx];
        half4v o;
        o.x = (_Float16)f.x; o.y = (_Float16)f.y; o.z = (_Float16)f.z; o.w = (_Float16)f.w;
        dst[idx] = o;
        return;
    }
    int idx = i - (n4a + n4b);
    if (idx >= NL * NK * HID * HID) return;
    int ii = idx & (HID - 1);
    int j = (idx >> 7) & (HID - 1);
    int kl = idx >> 14;          // l*3 + k
    int k = kl % 3;
    int l = kl / 3;
    w2t[((size_t)(l * HID + j)) * (NK * HID) + k * HID + ii] = (_Float16)fc_w[idx];
}

// -------------------------------------------------- fp16 MFMA GEMM, BM=64
// (round-11 winner: 64x128 tile, 4 waves, 782 blocks -> not grid-starved)
__global__ __launch_bounds__(256) void gemm_f16_kernel(
        const _Float16* __restrict__ A, const _Float16* __restrict__ W,
        const float* __restrict__ bias, _Float16* __restrict__ C16,
        float* __restrict__ bnsum, int M, int Kd) {
    __shared__ _Float16 sA[64 * 40], sB[128 * 40];    // stride 40 halfs
    __shared__ float bsum[HID], bsq[HID];
    int tid = threadIdx.x;
    if (bnsum && tid < HID) { bsum[tid] = 0.f; bsq[tid] = 0.f; }
    int bm = blockIdx.x * 64;
    int wave = tid >> 6, lane = tid & 63;
    int ln = lane & 15, quad = lane >> 4;
    int wy = wave >> 1, wx = wave & 1;
    int srow = tid >> 2, scol = (tid & 3) << 3;
    floatx4 acc[2][4] = {};
    const half8 zv = {0, 0, 0, 0, 0, 0, 0, 0};

    half8 pA, pB[2];
    bool av0 = (bm + srow) < M;
    const size_t aoff0 = (size_t)(bm + srow) * Kd + scol;
    const size_t woff0 = (size_t)srow * Kd + scol;
    const size_t woff1 = (size_t)(srow + 64) * Kd + scol;

#define LOAD_TILE(K0)                                                          \
    do {                                                                       \
        pB[0] = *(const half8*)(W + woff0 + (K0));                             \
        pB[1] = *(const half8*)(W + woff1 + (K0));                             \
        pA = av0 ? *(const half8*)(A + aoff0 + (K0)) : zv;                     \
    } while (0)

    LOAD_TILE(0);
    for (int k0 = 0; k0 < Kd; k0 += 32) {
        __syncthreads();
        *(half8*)&sA[srow * 40 + scol] = pA;
        *(half8*)&sB[srow * 40 + scol] = pB[0];
        *(half8*)&sB[(srow + 64) * 40 + scol] = pB[1];
        __syncthreads();
        if (k0 + 32 < Kd) LOAD_TILE(k0 + 32);   // overlaps with MFMA below
        half8 a[2], b[4];
        int kq = quad * 8;
#pragma unroll
        for (int i = 0; i < 2; ++i)
            a[i] = *(const half8*)&sA[(wy * 32 + i * 16 + ln) * 40 + kq];
#pragma unroll
        for (int j = 0; j < 4; ++j)
            b[j] = *(const half8*)&sB[(wx * 64 + j * 16 + ln) * 40 + kq];
#pragma unroll
        for (int i = 0; i < 2; ++i)
#pragma unroll
            for (int j = 0; j < 4; ++j)
                acc[i][j] = __builtin_amdgcn_mfma_f32_16x16x32_f16(a[i], b[j], acc[i][j], 0, 0, 0);
    }
#undef LOAD_TILE

    // epilogue: C/D layout col = lane&15, row = quad*4 + reg
#pragma unroll
    for (int j = 0; j < 4; ++j) {
        int gc = wx * 64 + j * 16 + ln;
        float bv = bias ? bias[gc] : 0.f;
#pragma unroll
        for (int i = 0; i < 2; ++i) {
#pragma unroll
            for (int r = 0; r < 4; ++r) {
                int gr = bm + wy * 32 + i * 16 + quad * 4 + r;
                if (gr < M) C16[(size_t)gr * HID + gc] = (_Float16)(acc[i][j][r] + bv);
            }
        }
    }
    if (bnsum) {
        // rows beyond M accumulated zeros (A loaded as 0, no bias) -> safe
#pragma unroll
        for (int j = 0; j < 4; ++j) {
            float s = 0.f, q = 0.f;
#pragma unroll
            for (int i = 0; i < 2; ++i)
#pragma unroll
                for (int r = 0; r < 4; ++r) { float v = acc[i][j][r]; s += v; q += v * v; }
            s += __shfl_xor(s, 16); s += __shfl_xor(s, 32);
            q += __shfl_xor(q, 16); q += __shfl_xor(q, 32);
            if (quad == 0) {
                atomicAdd(&bsum[wx * 64 + j * 16 + ln], s);
                atomicAdd(&bsq[wx * 64 + j * 16 + ln], q);
            }
        }
        __syncthreads();
        float* slice = bnsum + (blockIdx.x & (NSLICE - 1)) * (2 * HID);
        if (tid < HID) {
            atomicAdd(&slice[tid],       bsum[tid]);
            atomicAdd(&slice[HID + tid], bsq[tid]);
        }
    }
}

// ----------- CSR aggregation: per-node serial, 32-lane sub-groups + inline
// edge-weight recompute (round-8/12 winner).
__global__ __launch_bounds__(256) void aggregate_kernel(const int* __restrict__ csr_off,
                                                        const int* __restrict__ esrc,
                                                        const int* __restrict__ degr,
                                                        const int* __restrict__ degc,
                                                        const char* __restrict__ h16,
                                                        _Float16* __restrict__ u,
                                                        const float* __restrict__ pw,
                                                        const float* __restrict__ pb,
                                                        const float* __restrict__ mu,
                                                        const float* __restrict__ isg) {
    int wave = threadIdx.x >> 6;
    int lane = threadIdx.x & 63;
    int sub = lane >> 5;          // which node in the wave
    int sl = lane & 31;           // lane within 32-group
    int base = sub << 5;          // shfl source base
    int n = blockIdx.x * 8 + wave * 2 + sub;
    if (n >= N_NODES) return;
    int beg = csr_off[n], end = csr_off[n + 1];
    float py = rsqrtf((float)degc[n] + 1.0f);
    float pw0 = pw[0], pw1 = pw[1], pw2 = pw[2], pw3 = pw[3];
    float pb0 = pb[0], pb1 = pb[1];
    float m00 = mu[0], m01 = mu[1], m10 = mu[2], m11 = mu[3], m20 = mu[4], m21 = mu[5];
    float s00 = isg[0], s01 = isg[1], s10 = isg[2], s11 = isg[3], s20 = isg[4], s21 = isg[5];
    const char* hb = h16 + sl * 8;
    floatx4 a0 = {0.f, 0.f, 0.f, 0.f}, a1 = a0, a2 = a0;

    for (int chunk = beg; chunk < end; chunk += 32) {
        int ce = chunk + sl;
        int rsrc = (ce < end) ? esrc[ce] : 0;
        float px = rsqrtf((float)degr[rsrc] + 1.0f);
        int roff = rsrc << 8;     // byte offset into fp16 h row (256 B)
        float ps0 = tanh_fast(px * pw0 + py * pw1 + pb0);
        float ps1 = tanh_fast(px * pw2 + py * pw3 + pb1);
        float d0 = ps0 - m00, d1 = ps1 - m01;
        float w0 = __expf(-0.5f * (d0 * d0 * s00 * s00 + d1 * d1 * s01 * s01));
        d0 = ps0 - m10; d1 = ps1 - m11;
        float w1 = __expf(-0.5f * (d0 * d0 * s10 * s10 + d1 * d1 * s11 * s11));
        d0 = ps0 - m20; d1 = ps1 - m21;
        float w2 = __expf(-0.5f * (d0 * d0 * s20 * s20 + d1 * d1 * s21 * s21));
        int m = end - chunk; if (m > 32) m = 32;
        int t = 0;
        for (; t + 8 <= m; t += 8) {
            int ro[8];
#pragma unroll
            for (int s = 0; s < 8; ++s) ro[s] = __shfl(roff, base + t + s);
            half4v hv[8];
#pragma unroll
            for (int s = 0; s < 8; ++s) hv[s] = *(const half4v*)(hb + (unsigned)ro[s]);
#pragma unroll
            for (int s = 0; s < 8; ++s) {
                float wx = __shfl(w0, base + t + s);
                float wy = __shfl(w1, base + t + s);
                float wz = __shfl(w2, base + t + s);
                floatx4 hf = {(float)hv[s].x, (float)hv[s].y, (float)hv[s].z, (float)hv[s].w};
                a0 += wx * hf;
                a1 += wy * hf;
                a2 += wz * hf;
            }
        }
        for (; t < m; ++t) {
            int ro = __shfl(roff, base + t);
            float wx = __shfl(w0, base + t);
            float wy = __shfl(w1, base + t);
            float wz = __shfl(w2, base + t);
            half4v hv = *(const half4v*)(hb + (unsigned)ro);
            floatx4 hf = {(float)hv.x, (float)hv.y, (float)hv.z, (float)hv.w};
            a0 += wx * hf;
            a1 += wy * hf;
            a2 += wz * hf;
        }
    }
    size_t b = (size_t)n * 384 + sl * 4;
    half4v o0, o1, o2;
    o0.x = (_Float16)a0.x; o0.y = (_Float16)a0.y; o0.z = (_Float16)a0.z; o0.w = (_Float16)a0.w;
    o1.x = (_Float16)a1.x; o1.y = (_Float16)a1.y; o1.z = (_Float16)a1.z; o1.w = (_Float16)a1.w;
    o2.x = (_Float16)a2.x; o2.y = (_Float16)a2.y; o2.z = (_Float16)a2.z; o2.w = (_Float16)a2.w;
    *(half4v*)(u + b)       = o0;
    *(half4v*)(u + b + 128) = o1;
    *(half4v*)(u + b + 256) = o2;
}

// ------- BN finalize (per-block redundant, bit-identical to old bn_finalize)
// + apply (fused scale/shift) + ReLU + residual. Grid-stride at 1024 blocks
// caps the redundant slice-reduction L2 traffic at ~32 MB (~1 us).
__global__ __launch_bounds__(256) void bn_apply_kernel(half4v* __restrict__ h16,
                                                       const half4v* __restrict__ agg16,
                                                       const float* __restrict__ slices,
                                                       const float* __restrict__ gamma,
                                                       const float* __restrict__ beta) {
    __shared__ float sc[HID], sh[HID];
    int tid = threadIdx.x;
    if (tid < HID) {
        float s = 0.f, q = 0.f;
        for (int z = 0; z < NSLICE; ++z) {
            s += slices[z * (2 * HID) + tid];
            q += slices[z * (2 * HID) + HID + tid];
        }
        const float invN = 1.0f / (float)N_NODES;
        float mean = s * invN;
        float var = q * invN - mean * mean;
        float scale = gamma[tid] * rsqrtf(var + BN_EPS);
        sc[tid] = scale;
        sh[tid] = beta[tid] - mean * scale;
    }
    __syncthreads();
    const int total = N_NODES * HID / 4;
    for (int idx = blockIdx.x * 256 + tid; idx < total; idx += gridDim.x * 256) {
        int c = (idx & 31) * 4;
        half4v a = agg16[idx];
        half4v hv = h16[idx];
        half4v o16;
#pragma unroll
        for (int j = 0; j < 4; ++j) {
            float hn = (float)a[j] * sc[c + j] + sh[c + j];
            o16[j] = (_Float16)((float)hv[j] + fmaxf(hn, 0.f));
        }
        h16[idx] = o16;
    }
}

// -------------------------------------------- fused readout + 3-layer MLP
// Now ALSO fuses the final layer's BN+ReLU+residual: reads pre-update h16
// and layer-3 agg16, computes h_in + relu(bn(agg)) on the fly (the final
// h16 write existed only to feed this sum). Threads 0-127 build sc/sh.
__global__ __launch_bounds__(1024) void readout_mlp_kernel(const _Float16* __restrict__ h16,
                                                           const _Float16* __restrict__ agg16,
                                                           const float* __restrict__ slices,
                                                           const float* __restrict__ gammaL,
                                                           const float* __restrict__ betaL,
                                                           const int* __restrict__ batch,
                                                           const float* __restrict__ w0, const float* __restrict__ b0,
                                                           const float* __restrict__ w1, const float* __restrict__ b1,
                                                           const float* __restrict__ w2, const float* __restrict__ b2,
                                                           float* __restrict__ out) {
    __shared__ float sc[HID], sh[HID];
    __shared__ float part[8][128];
    __shared__ float hg[128];
    __shared__ float z0[64];
    __shared__ float z1[32];
    __shared__ int range[2];
    int g = blockIdx.x;
    int tid = threadIdx.x;
    if (tid < HID) {
        float s = 0.f, q = 0.f;
        for (int z = 0; z < NSLICE; ++z) {
            s += slices[z * (2 * HID) + tid];
            q += slices[z * (2 * HID) + HID + tid];
        }
        const float invN = 1.0f / (float)N_NODES;
        float mean = s * invN;
        float var = q * invN - mean * mean;
        float scale = gammaL[tid] * rsqrtf(var + BN_EPS);
        sc[tid] = scale;
        sh[tid] = betaL[tid] - mean * scale;
    }
    if (tid == 0) {
        int lo = 0, hi = N_NODES;
        while (lo < hi) { int mid = (lo + hi) >> 1; if (batch[mid] < g) lo = mid + 1; else hi = mid; }
        range[0] = lo;
        hi = N_NODES;
        while (lo < hi) { int mid = (lo + hi) >> 1; if (batch[mid] < g + 1) lo = mid + 1; else hi = mid; }
        range[1] = lo;
    }
    __syncthreads();
    int lo = range[0], hi = range[1];
    int rg = tid >> 7;            // row-group 0..7
    int ch = tid & 127;           // channel
    float scv = sc[ch], shv = sh[ch];
    float s0 = 0.f, s1 = 0.f, s2 = 0.f, s3 = 0.f;
    int n = lo + rg;
#define ROWVAL(N_) ((float)h16[(size_t)(N_) * HID + ch] + \
                    fmaxf((float)agg16[(size_t)(N_) * HID + ch] * scv + shv, 0.f))
    for (; n + 24 < hi; n += 32) {
        s0 += ROWVAL(n);
        s1 += ROWVAL(n + 8);
        s2 += ROWVAL(n + 16);
        s3 += ROWVAL(n + 24);
    }
    for (; n < hi; n += 8) s0 += ROWVAL(n);
#undef ROWVAL
    part[rg][ch] = (s0 + s1) + (s2 + s3);
    __syncthreads();
    if (tid < 128) {
        float s = 0.f;
#pragma unroll
        for (int r = 0; r < 8; ++r) s += part[r][tid];
        int cnt = hi - lo; if (cnt < 1) cnt = 1;
        hg[tid] = s / (float)cnt;
    }
    __syncthreads();
    if (tid < 64) {
        float a = b0[tid];
        for (int i = 0; i < 128; ++i) a += hg[i] * w0[tid * 128 + i];
        z0[tid] = fmaxf(a, 0.f);
    }
    __syncthreads();
    if (tid < 32) {
        float a = b1[tid];
        for (int i = 0; i < 64; ++i) a += z0[i] * w1[tid * 64 + i];
        z1[tid] = fmaxf(a, 0.f);
    }
    __syncthreads();
    if (tid < 10) {
        float a = b2[tid];
        for (int i = 0; i < 32; ++i) a += z1[i] * w2[tid * 32 + i];
        out[g * NC + tid] = a;
    }
}

// ----------------------------------------------------------------- launch
extern "C" void kernel_launch(void* const* d_in, const int* in_sizes, int n_in,
                              void* d_out, int out_size, void* d_ws, size_t ws_size,
                              hipStream_t stream) {
    const float* feature = (const float*)d_in[0];
    const int*   edge    = (const int*)d_in[1];
    const int*   row     = edge;
    const int*   col     = edge + N_EDGES;
    const int*   batch   = (const int*)d_in[2];
    const float* emb_w   = (const float*)d_in[3];
    const float* emb_b   = (const float*)d_in[4];
    const float* fc_w    = (const float*)d_in[5];
    const float* mu      = (const float*)d_in[6];
    const float* isig    = (const float*)d_in[7];
    const float* gamma   = (const float*)d_in[8];
    const float* beta    = (const float*)d_in[9];
    const float* pp_w    = (const float*)d_in[10];
    const float* pp_b    = (const float*)d_in[11];
    const float* mw0     = (const float*)d_in[12];
    const float* mb0     = (const float*)d_in[13];
    const float* mw1     = (const float*)d_in[14];
    const float* mb1     = (const float*)d_in[15];
    const float* mw2     = (const float*)d_in[16];
    const float* mb2     = (const float*)d_in[17];
    float* out = (float*)d_out;

    // workspace carve-up (256B aligned)
    char* ws = (char*)d_ws;
    size_t off = 0;
    auto carve = [&](size_t bytes) { size_t o = off; off = (off + bytes + 255) & ~(size_t)255; return o; };
    _Float16* h16   = (_Float16*)(ws + carve((size_t)N_NODES * HID * 2));
    _Float16* u     = (_Float16*)(ws + carve((size_t)N_NODES * NK * HID * 2));
    _Float16* agg16 = (_Float16*)(ws + carve((size_t)N_NODES * HID * 2));
    int* esrc       = (int*)(ws + carve((size_t)N_EDGES * 4));
    _Float16* w2t   = (_Float16*)(ws + carve((size_t)NL * HID * NK * HID * 2));
    _Float16* f16   = (_Float16*)(ws + carve((size_t)N_NODES * HID * 2));
    _Float16* e16   = (_Float16*)(ws + carve((size_t)HID * HID * 2));
    int* degr       = (int*)(ws + carve((size_t)N_NODES * 4));
    int* degc       = (int*)(ws + carve((size_t)N_NODES * 4));
    int* csr_off    = (int*)(ws + carve((size_t)(N_NODES + 1) * 4));
    int* cursor     = (int*)(ws + carve((size_t)N_NODES * 4));
    int* blocksum   = (int*)(ws + carve((size_t)SCAN_G * 4));
    unsigned* pr    = (unsigned*)(ws + carve((size_t)H_CHK * PKW * 4));
    unsigned* pc    = (unsigned*)(ws + carve((size_t)H_CHK * PKW * 4));
    float* bnsum    = (float*)(ws + carve((size_t)NL * NSLICE * 2 * HID * 4));
    (void)ws_size; (void)in_sizes; (void)n_in; (void)out_size;

    hipMemsetAsync(bnsum, 0, (size_t)NL * NSLICE * 2 * HID * 4, stream);

    hist_lds_kernel<<<dim3(H_CHK, 2), 256, 0, stream>>>(row, col, pr, pc);
    hist_reduce_kernel<<<(PKW + 255) / 256, 256, 0, stream>>>(pr, pc, degr, degc);
    scan1_kernel<<<SCAN_G, 256, 0, stream>>>(degc, csr_off, blocksum);
    scan2_kernel<<<1, 256, 0, stream>>>(blocksum);
    scan3_kernel<<<SCAN_G, 256, 0, stream>>>(blocksum, csr_off, cursor);
    fill_src_kernel<<<FP_CHK * 8, 256, 0, stream>>>(col, row, cursor, esrc);

    prep16_kernel<<<((N_NODES * HID + HID * HID) / 4 + NL * NK * HID * HID + 255) / 256,
                    256, 0, stream>>>(
        (const float4*)feature, N_NODES * HID / 4, (const float4*)emb_w, HID * HID / 4,
        (half4v*)f16, (half4v*)e16, fc_w, w2t);

    // h16 = feature @ emb_w^T + emb_b
    gemm_f16_kernel<<<(N_NODES + 63) / 64, 256, 0, stream>>>(
        f16, e16, emb_b, h16, nullptr, N_NODES, HID);

    for (int l = 0; l < NL; ++l) {
        aggregate_kernel<<<(N_NODES + 7) / 8, 256, 0, stream>>>(
            csr_off, esrc, degr, degc, (const char*)h16, u,
            pp_w + l * 4, pp_b + l * 2, mu + l * 6, isig + l * 6);
        gemm_f16_kernel<<<(N_NODES + 63) / 64, 256, 0, stream>>>(
            u, w2t + (size_t)l * HID * NK * HID, nullptr, agg16,
            bnsum + (size_t)l * NSLICE * 2 * HID, N_NODES, NK * HID);
        if (l < NL - 1) {
            bn_apply_kernel<<<1024, 256, 0, stream>>>(
                (half4v*)h16, (const half4v*)agg16,
                bnsum + (size_t)l * NSLICE * 2 * HID, gamma + l * HID, beta + l * HID);
        }
    }

    // final layer's BN+ReLU+residual fused into the readout
    readout_mlp_kernel<<<N_GRAPHS, 1024, 0, stream>>>(
        h16, agg16, bnsum + (size_t)(NL - 1) * NSLICE * 2 * HID,
        gamma + (NL - 1) * HID, beta + (NL - 1) * HID,
        batch, mw0, mb0, mw1, mb1, mw2, mb2, out);
}